// Round 3
// baseline (292.298 us; speedup 1.0000x reference)
//
#include <hip/hip_runtime.h>
#include <type_traits>

// ---------------------------------------------------------------------------
// MultiHeadAttention fused pipeline for MI355X (gfx950)
// x[B,S,E] @ w_qkv -> split QKV -> RoPE -> causal GQA flash attention -> @ w_dense
// B=2 S=2048 E=2048 H=16 KVH=4 D=128
// R11: GEMM ported to the 256x256 8-phase counted-vmcnt template (T2+T3+T4+T5).
//      Old 128x128 2-barrier structure measured 853 TF (its known ~900 ceiling:
//      vmcnt(0) drain at every barrier). New: 512 thr / 8 waves (2Mx4N), per-wave
//      128x64, BK=64, LDS 128KB dbuf (dynamic). Per K-tile: 4 phases, each
//      {ds_read subtile || stage one 16KB half (2x gload_lds/wave) || barrier ||
//      lgkmcnt(0) || setprio(1) 16 MFMA setprio(0) || barrier}; vmcnt(6) only at
//      phases 4/8 -> 3 half-tiles always in flight. LDS tiles stored mh/nh-major
//      so each staged half is read by exactly one phase (write-after-read safe).
//      Same K order -> bit-identical outputs.
// R10: attn register-resident P via kv-permuted VT (see attn comment).
// ---------------------------------------------------------------------------

typedef __attribute__((ext_vector_type(8))) short short8;
typedef __attribute__((ext_vector_type(4))) float floatx4;
typedef __attribute__((ext_vector_type(4))) unsigned short ushort4v;
typedef __attribute__((ext_vector_type(4))) unsigned int uint4v;

constexpr int NH    = 16;
constexpr int NKV   = 4;
constexpr int HD    = 128;
constexpr int SEQ   = 2048;
constexpr int EMB   = 2048;
constexpr int NBATCH = 2;
constexpr int MROWS = NBATCH * SEQ;          // 4096
constexpr int NQKV  = (NH + 2 * NKV) * HD;   // 3072

__device__ __forceinline__ unsigned short f2b(float f) {
  union { float f; unsigned u; } v; v.f = f;
  unsigned u = v.u + 0x7FFFu + ((v.u >> 16) & 1u);   // RNE
  return (unsigned short)(u >> 16);
}
__device__ __forceinline__ float b2f(unsigned short h) {
  union { unsigned u; float f; } v; v.u = (unsigned)h << 16;
  return v.f;
}

// async global->LDS DMA, 16B per lane; lds dest = uniform base + lane*16
__device__ __forceinline__ void gload_lds16(const unsigned short* g,
                                            unsigned short* lds) {
  __builtin_amdgcn_global_load_lds(
      (const __attribute__((address_space(1))) unsigned int*)g,
      (__attribute__((address_space(3))) unsigned int*)lds, 16, 0, 0);
}

// --------------------------- fp32 -> bf16 cast ------------------------------
__global__ void cvt_f32_bf16(const float* __restrict__ in,
                             unsigned short* __restrict__ out, int n) {
  int i = (blockIdx.x * 256 + threadIdx.x) * 4;
  if (i + 3 < n) {
    floatx4 v = *(const floatx4*)(in + i);
    ushort4v o = { f2b(v[0]), f2b(v[1]), f2b(v[2]), f2b(v[3]) };
    *(ushort4v*)(out + i) = o;
  }
}

// ---------- fp32 [R][C] -> bf16 [C][R] transpose, both weights in one -------
__global__ void transpose_cvt_dual(const float* __restrict__ wqkv,
                                   unsigned short* __restrict__ oqkv,
                                   const float* __restrict__ wd,
                                   unsigned short* __restrict__ od) {
  const int z = blockIdx.z;
  const float* in = z ? wd : wqkv;
  unsigned short* out = z ? od : oqkv;
  const int R = EMB;                       // both weights have 2048 rows
  const int C = z ? EMB : NQKV;
  int c0 = blockIdx.x * 32, r0 = blockIdx.y * 32;
  if (c0 >= C) return;
  __shared__ float t[32][33];
  int tx = threadIdx.x & 31, ty = threadIdx.x >> 5;  // ty 0..7
#pragma unroll
  for (int i = 0; i < 32; i += 8)
    t[ty + i][tx] = in[(long)(r0 + ty + i) * C + (c0 + tx)];
  __syncthreads();
#pragma unroll
  for (int i = 0; i < 32; i += 8)
    out[(long)(c0 + ty + i) * R + (r0 + tx)] = f2b(t[tx][ty + i]);
}

// ------------------------- RoPE (in-place, Q and K) -------------------------
__global__ void rope_kernel(unsigned short* __restrict__ Qb,
                            unsigned short* __restrict__ Kb, float qscale) {
  int idx = blockIdx.x * 256 + threadIdx.x;
  int i = idx & 63;
  int s = (idx >> 6) & (SEQ - 1);
  int bh = idx >> 17;                       // SEQ*64 = 1<<17
  unsigned short* p;
  float scale;
  if (bh < NBATCH * NH) { p = Qb + ((long)bh * SEQ + s) * HD; scale = qscale; }
  else { p = Kb + ((long)(bh - NBATCH * NH) * SEQ + s) * HD; scale = 1.0f; }
  float e = -(float)i * (2.0f * 13.287712379549449f / 128.0f);
  float ang = (float)s * exp2f(e);
  float sn, c;
  sincosf(ang, &sn, &c);
  float x1 = b2f(p[i]), x2 = b2f(p[i + 64]);
  p[i]      = f2b((x1 * c - x2 * sn) * scale);
  p[i + 64] = f2b((x2 * c + x1 * sn) * scale);
}

// ------------------------------- GEMM (B^T) ---------------------------------
// C[M][N] = A[M][K](bf16) * BT[N][K](bf16)^T.  256x256 tile, 8 waves of 128x64,
// BK=64, 8-phase counted-vmcnt schedule, XOR-swizzled LDS (16B block ^ row&7).
// LDS layout (shorts): As[buf=2][256*64] at 0, Bs[buf=2][256*64] at 32768.
// A LDS row = mh*128 + wr*64 + mi*16 + l  <->  global m = wr*128 + mh*64 + ...
// B LDS row = nh*128 + wc*32 + ni*16 + l  <->  global n = wc*64 + nh*32 + ...
// so staged halves [h*128, h*128+128) are consumed by exactly one phase.
// MODE 0: Q/K tiles -> Ct[256][256] LDS repack, 16B head-major stores;
//         V tiles  -> transposed kv-permuted ushort4 stores into VT[d][s].
// MODE 1: fp32 dense store to outF.

#define G_BARRIER __builtin_amdgcn_s_barrier()
#define G_LGKM0 asm volatile("s_waitcnt lgkmcnt(0)" ::: "memory")
#define G_LGKM8 asm volatile("s_waitcnt lgkmcnt(8)" ::: "memory")
#define G_VM(N) asm volatile("s_waitcnt vmcnt(" #N ")" ::: "memory")

#define READ_A(BUF, MH)                                                        \
  _Pragma("unroll") for (int kk = 0; kk < 2; ++kk)                             \
  _Pragma("unroll") for (int mi = 0; mi < 4; ++mi)                             \
    af[kk][mi] = *(const short8*)&sm[(BUF)*16384 +                             \
        ((MH)*128 + wr64 + mi*16 + l)*64 + kb[kk]];

#define READ_B(BUF, NH)                                                        \
  _Pragma("unroll") for (int kk = 0; kk < 2; ++kk)                             \
  _Pragma("unroll") for (int ni = 0; ni < 2; ++ni)                             \
    bf[NH][kk][ni] = *(const short8*)&sm[32768 + (BUF)*16384 +                 \
        ((NH)*128 + wc32 + ni*16 + l)*64 + kb[kk]];

#define MFMA_SECT(MH, NH)                                                      \
  G_BARRIER;                                                                   \
  G_LGKM0;                                                                     \
  __builtin_amdgcn_s_setprio(1);                                               \
  _Pragma("unroll") for (int kk = 0; kk < 2; ++kk)                             \
  _Pragma("unroll") for (int mi = 0; mi < 4; ++mi)                             \
  _Pragma("unroll") for (int ni = 0; ni < 2; ++ni)                             \
    acc[MH][mi][NH][ni] = __builtin_amdgcn_mfma_f32_16x16x32_bf16(             \
        af[kk][mi], bf[NH][kk][ni], acc[MH][mi][NH][ni], 0, 0, 0);             \
  __builtin_amdgcn_s_setprio(0);                                               \
  G_BARRIER

template <int MODE>
__global__ __launch_bounds__(512, 2) void gemm_bt(
    const unsigned short* __restrict__ A,
    const unsigned short* __restrict__ BT,
    int Mdim, int Ndim, int Kdim,
    float* __restrict__ outF,
    unsigned short* __restrict__ Qb,
    unsigned short* __restrict__ Kb,
    unsigned short* __restrict__ Vt) {
  extern __shared__ __align__(16) unsigned short sm[];   // 128 KB dynamic
  const int tid = threadIdx.x;
  const int wave = tid >> 6, lane = tid & 63;
  const int l = lane & 15, q = lane >> 4;
  const int l7 = l & 7;
  const int wr = wave >> 2, wc = wave & 3;   // 2M x 4N wave grid
  const int wr64 = wr * 64, wc32 = wc * 32;
  const int bm = blockIdx.y * 256;
  const int bn = blockIdx.x * 256;
  const int srow = lane >> 3;                    // 0..7
  const int scol = ((lane & 7) ^ srow) * 8;      // swizzled source col (shorts)
  const int kb[2] = { (q ^ l7) * 8, ((4 + q) ^ l7) * 8 };

  floatx4 acc[2][4][2][2] = {};   // [mh][mi][nh][ni]
  short8 af[2][4];                // [kk][mi]
  short8 bf[2][2][2];             // [nh][kk][ni]

  // stage one 16KB A-half: LDS rows [h*128, h*128+128) of As[buf]
  auto stA = [&](int buf, int h, int kt) {
    const unsigned short* s0 = A +
        (long)(bm + (wave >> 2) * 128 + h * 64 + (wave & 3) * 16 + srow) * Kdim +
        kt * 64 + scol;
    unsigned short* d0 = &sm[buf * 16384 + (h * 128 + wave * 16) * 64];
    gload_lds16(s0, d0);
    gload_lds16(s0 + 8L * Kdim, d0 + 8 * 64);
  };
  auto stB = [&](int buf, int h, int kt) {
    const unsigned short* s0 = BT +
        (long)(bn + (wave >> 1) * 64 + h * 32 + (wave & 1) * 16 + srow) * Kdim +
        kt * 64 + scol;
    unsigned short* d0 = &sm[32768 + buf * 16384 + (h * 128 + wave * 16) * 64];
    gload_lds16(s0, d0);
    gload_lds16(s0 + 8L * Kdim, d0 + 8 * 64);
  };

  // ---- prologue: kt0 complete + A0,B1,A1 of kt1 in flight (3 halves) ----
  stA(0, 0, 0); stB(0, 0, 0); stB(0, 1, 0); stA(0, 1, 0);
  G_VM(4);
  stA(1, 0, 1); stB(1, 1, 1); stA(1, 1, 1);
  G_VM(6);
  G_BARRIER;

  const int niter = Kdim / 128 - 1;   // 15 full iterations, then drain
#pragma unroll 1
  for (int i = 0; i < niter; ++i) {
    const int kt = 2 * i;
    // ph1: quad(0,0) buf0; stage B0 kt+1 -> buf1
    READ_A(0, 0) READ_B(0, 0) stB(1, 0, kt + 1); G_LGKM8; MFMA_SECT(0, 0);
    // ph2: quad(0,1) buf0; stage A0 kt+2 -> buf0 (A0 freed at ph1)
    READ_B(0, 1) stA(0, 0, kt + 2); MFMA_SECT(0, 1);
    // ph3: quad(1,1) buf0; stage B1 kt+2 -> buf0 (B1 freed at ph2)
    READ_A(0, 1) stB(0, 1, kt + 2); MFMA_SECT(1, 1);
    // ph4: quad(1,0) buf0 (regs only); stage A1 kt+2 -> buf0; vmcnt(6)
    stA(0, 1, kt + 2); G_VM(6); MFMA_SECT(1, 0);
    // ph5: quad(0,0) buf1; stage B0 kt+2 -> buf0 (B0 freed at ph1)
    READ_A(1, 0) READ_B(1, 0) stB(0, 0, kt + 2); G_LGKM8; MFMA_SECT(0, 0);
    // ph6: quad(0,1) buf1; stage A0 kt+3 -> buf1 (freed at ph5)
    READ_B(1, 1) stA(1, 0, kt + 3); MFMA_SECT(0, 1);
    // ph7: quad(1,1) buf1; stage B1 kt+3 -> buf1 (freed at ph6)
    READ_A(1, 1) stB(1, 1, kt + 3); MFMA_SECT(1, 1);
    // ph8: quad(1,0) buf1; stage A1 kt+3 -> buf1; vmcnt(6)
    stA(1, 1, kt + 3); G_VM(6); MFMA_SECT(1, 0);
  }
  { // drain: buf0 = kt, buf1 = kt+1 (last two K-tiles)
    const int kt = 2 * niter;
    READ_A(0, 0) READ_B(0, 0) stB(1, 0, kt + 1); G_LGKM8; MFMA_SECT(0, 0);
    READ_B(0, 1) G_VM(4); MFMA_SECT(0, 1);
    READ_A(0, 1) G_VM(2); MFMA_SECT(1, 1);
    G_VM(0); MFMA_SECT(1, 0);
    READ_A(1, 0) READ_B(1, 0) G_LGKM8; MFMA_SECT(0, 0);
    READ_B(1, 1) MFMA_SECT(0, 1);
    READ_A(1, 1) MFMA_SECT(1, 1);
    MFMA_SECT(1, 0);
  }

  if constexpr (MODE == 1) {
#pragma unroll
    for (int mh = 0; mh < 2; ++mh)
#pragma unroll
      for (int mi = 0; mi < 4; ++mi) {
        const int rowb = bm + wr * 128 + mh * 64 + mi * 16 + q * 4;
#pragma unroll
        for (int nh = 0; nh < 2; ++nh)
#pragma unroll
          for (int ni = 0; ni < 2; ++ni) {
            const int col = bn + wc * 64 + nh * 32 + ni * 16 + l;
#pragma unroll
            for (int r = 0; r < 4; ++r)
              outF[(long)(rowb + r) * Ndim + col] = acc[mh][mi][nh][ni][r];
          }
      }
  } else if (bn >= (NH + NKV) * HD) {
    // ---- V tiles (2 heads per 256-tile): transposed kv-permuted stores ----
    const int hh0 = (bn - (NH + NKV) * HD) >> 7;
#pragma unroll
    for (int mh = 0; mh < 2; ++mh)
#pragma unroll
      for (int mi = 0; mi < 4; ++mi) {
        const int m0 = bm + wr * 128 + mh * 64 + mi * 16 + q * 4;
        const int bb = m0 >> 11, s = m0 & (SEQ - 1);
        const int s6 = s & 63;                 // bits[1:0]=0 (q*4 aligned)
        const int p6 = (s6 & 32) | ((s6 & 12) << 1) | ((s6 & 16) >> 2);
        const long spb = (long)((s & ~63) | p6);
#pragma unroll
        for (int nh = 0; nh < 2; ++nh)
#pragma unroll
          for (int ni = 0; ni < 2; ++ni) {
            const int col = wc * 64 + nh * 32 + ni * 16 + l;
            const int hh = hh0 + (col >> 7), d = col & 127;
            unsigned short* vtb = Vt + ((long)(bb * NKV + hh)) * HD * SEQ;
            ushort4v pv = { f2b(acc[mh][mi][nh][ni][0]), f2b(acc[mh][mi][nh][ni][1]),
                            f2b(acc[mh][mi][nh][ni][2]), f2b(acc[mh][mi][nh][ni][3]) };
            *(ushort4v*)(vtb + (long)d * SEQ + spb) = pv;
          }
      }
  } else {
    // ---- Q/K tiles: repack via Ct[256][256] (128 KB = whole smem) ----
    // 16B-block swizzle: phys = (blk & 24) | ((blk ^ row) & 7)
    unsigned short* Ct = sm;
#pragma unroll
    for (int mh = 0; mh < 2; ++mh)
#pragma unroll
      for (int mi = 0; mi < 4; ++mi)
#pragma unroll
        for (int nh = 0; nh < 2; ++nh)
#pragma unroll
          for (int ni = 0; ni < 2; ++ni)
#pragma unroll
            for (int r = 0; r < 4; ++r) {
              const int row = wr * 128 + mh * 64 + mi * 16 + q * 4 + r;
              const int col = wc * 64 + nh * 32 + ni * 16 + l;
              const int blk = col >> 3;
              const int cs = ((blk & 24) | ((blk ^ row) & 7)) * 8 + (col & 7);
              Ct[row * 256 + cs] = f2b(acc[mh][mi][nh][ni][r]);
            }
    __syncthreads();
    const int row = tid >> 1, g = tid & 1;
    const int m = bm + row, bb = m >> 11, s = m & (SEQ - 1);
    const int hg = (bn >> 7) + g;              // 128-col group = one head
    unsigned short* dst;
    if (hg < NH) dst = Qb + (((long)(bb * NH + hg)) * SEQ + s) * HD;
    else         dst = Kb + (((long)(bb * NKV + (hg - NH))) * SEQ + s) * HD;
#pragma unroll
    for (int i = 0; i < 16; ++i) {
      const int blk = g * 16 + i;
      const int pb = (blk & 24) | ((blk ^ row) & 7);
      *(short8*)(dst + i * 8) = *(const short8*)&Ct[row * 256 + pb * 8];
    }
  }
}

// --------------------------- flash attention --------------------------------
// R10 structure: 128-row q-tiles, 4 waves x 32 q-rows (2 mh sub-tiles of 16).
// Swapped QK^T (sf = mfma(K,Q)) -> lane holds P[kv=ni*16+q*4+r][qrow=l].
// P stays in registers: cvt_pk pairs -> 4 u32 = short8 = PV A-fragment under
// the kv-permutation baked into VT's global layout (see gemm V-epilogue).
// LDS: Ks 32K + VTs 32K = 64KB -> 2 blocks/CU.
__global__ __launch_bounds__(256, 2) void attn_kernel(
    const unsigned short* __restrict__ Q,   // [B][NH][S][D], pre-scaled by 1/sqrt(d)*log2e
    const unsigned short* __restrict__ K,   // [B][NKV][S][D]
    const unsigned short* __restrict__ VT,  // [B][NKV][D][S], kv-permuted per 64
    unsigned short* __restrict__ attn) {    // [B*S][NH*D]
  const int h = blockIdx.y, b = blockIdx.z;
  const int t = b ? (15 - (int)blockIdx.x) : (int)blockIdx.x;  // q-tile (128 rows)
  const int kvh = h >> 2;   // jnp.repeat: q head h uses kv head h/4
  const int tid = threadIdx.x;
  const int wave = tid >> 6, lane = tid & 63;
  const int l = lane & 15, q = lane >> 4;
  const int l7 = l & 7;
  const int wq = wave * 32;

  const unsigned short* Kh  = K  + ((long)(b * NKV + kvh)) * SEQ * HD;
  const unsigned short* VTh = VT + ((long)(b * NKV + kvh)) * HD * SEQ;

  __shared__ __align__(16) unsigned short smem[2 * 64 * 128 + 2 * 128 * 64]; // 64 KB
  unsigned short (*Ks)[64 * 128]  = (unsigned short (*)[64 * 128])smem;
  unsigned short (*VTs)[128 * 64] = (unsigned short (*)[128 * 64])(smem + 2 * 64 * 128);

  int koff[4], voff[4];
  {
    const int k_rl = lane >> 4, k_bp = lane & 15;
    const int v_rl = lane >> 3, v_bp = lane & 7;
#pragma unroll
    for (int j = 0; j < 4; ++j) {
      const int rk = (wave * 4 + j) * 4 + k_rl;
      koff[j] = rk * HD + (k_bp ^ (rk & 15)) * 8;
      const int rv = (wave * 4 + j) * 8 + v_rl;
      voff[j] = rv * SEQ + (v_bp ^ (rv & 7)) * 8;
    }
  }

  short8 onesf;
#pragma unroll
  for (int i = 0; i < 8; ++i) onesf[i] = (short)0x3F80;   // bf16 1.0

  auto stage = [&](int c, int buf) {
    const unsigned short* kc = Kh + c * (64 * HD);
    const unsigned short* vc = VTh + c * 64;
#pragma unroll
    for (int j = 0; j < 4; ++j)
      gload_lds16(kc + koff[j], &Ks[buf][(wave * 4 + j) * 4 * 128]);
#pragma unroll
    for (int j = 0; j < 4; ++j)
      gload_lds16(vc + voff[j], &VTs[buf][(wave * 4 + j) * 8 * 64]);
  };

  const unsigned short* Qh = Q + (((long)(b * NH + h)) * SEQ + t * 128) * HD;
  short8 qf[2][4];
#pragma unroll
  for (int mh = 0; mh < 2; ++mh)
#pragma unroll
    for (int kk = 0; kk < 4; ++kk)
      qf[mh][kk] = *(const short8*)(Qh + (long)(wq + mh * 16 + l) * HD + kk * 32 + q * 8);

  floatx4 o[2][9] = {};   // [mh][0..7]=O d-tiles, [8]=denominator (ones col)

  auto chunk_body = [&](auto masked, int cur, int kv0) {
    constexpr bool MASKED = decltype(masked)::value;
    floatx4 sf[2][4] = {};
#pragma unroll
    for (int kk = 0; kk < 4; ++kk) {
      short8 kf[4];
#pragma unroll
      for (int ni = 0; ni < 4; ++ni)
        kf[ni] = *(const short8*)&Ks[cur][(ni * 16 + l) * 128 + (((kk * 4 + q) ^ l) * 8)];
#pragma unroll
      for (int mh = 0; mh < 2; ++mh)
#pragma unroll
        for (int ni = 0; ni < 4; ++ni)
          sf[mh][ni] = __builtin_amdgcn_mfma_f32_16x16x32_bf16(
              kf[ni], qf[mh][kk], sf[mh][ni], 0, 0, 0);
    }
    short8 pf[2][2];
#pragma unroll
    for (int mh = 0; mh < 2; ++mh) {
      const int qrow = t * 128 + wq + mh * 16 + l;
      unsigned u[8];
#pragma unroll
      for (int ni = 0; ni < 4; ++ni) {
        if constexpr (MASKED) {
#pragma unroll
          for (int r = 0; r < 4; ++r)
            if (kv0 + ni * 16 + q * 4 + r > qrow) sf[mh][ni][r] = -3e38f;  // exp2 -> 0
        }
        float e0 = exp2f(sf[mh][ni][0]);
        float e1 = exp2f(sf[mh][ni][1]);
        float e2 = exp2f(sf[mh][ni][2]);
        float e3 = exp2f(sf[mh][ni][3]);
        asm("v_cvt_pk_bf16_f32 %0, %1, %2" : "=v"(u[ni * 2]) : "v"(e0), "v"(e1));
        asm("v_cvt_pk_bf16_f32 %0, %1, %2" : "=v"(u[ni * 2 + 1]) : "v"(e2), "v"(e3));
      }
      union { uint4v v; short8 s; } a0, a1;
      a0.v = (uint4v){u[0], u[1], u[2], u[3]};
      a1.v = (uint4v){u[4], u[5], u[6], u[7]};
      pf[mh][0] = a0.s;   // kv-slots: pi(8q+j) = q*4+(j&3) + (j>=4)*16
      pf[mh][1] = a1.s;   // + 32
    }
#pragma unroll
    for (int c2 = 0; c2 < 2; ++c2) {
      const int pb = ((c2 * 4 + q) ^ l7) * 8;
#pragma unroll
      for (int di = 0; di < 8; ++di) {
        short8 vf = *(const short8*)&VTs[cur][(di * 16 + l) * 64 + pb];
        o[0][di] = __builtin_amdgcn_mfma_f32_16x16x32_bf16(pf[0][c2], vf, o[0][di], 0, 0, 0);
        o[1][di] = __builtin_amdgcn_mfma_f32_16x16x32_bf16(pf[1][c2], vf, o[1][di], 0, 0, 0);
      }
      o[0][8] = __builtin_amdgcn_mfma_f32_16x16x32_bf16(pf[0][c2], onesf, o[0][8], 0, 0, 0);
      o[1][8] = __builtin_amdgcn_mfma_f32_16x16x32_bf16(pf[1][c2], onesf, o[1][8], 0, 0, 0);
    }
  };

  const int nc = 2 * t + 2;   // causal: kv up to 128t+127, Tk=64
  stage(0, 0);
  __syncthreads();

  int c = 0;
#pragma unroll 1
  for (; c < nc - 2; ++c) {
    stage(c + 1, (c & 1) ^ 1);
    chunk_body(std::false_type{}, c & 1, c * 64);
    __syncthreads();   // prefetch DMA drained; all reads of cur done
  }
  stage(c + 1, (c & 1) ^ 1);
  chunk_body(std::true_type{}, c & 1, c * 64);
  __syncthreads();
  ++c;
  chunk_body(std::true_type{}, c & 1, c * 64);
  __syncthreads();     // all waves done reading Ks/VTs before repack overwrite

  unsigned short (*Ob)[136] = (unsigned short (*)[136])smem;  // 34.8 KB < 64 KB
#pragma unroll
  for (int mh = 0; mh < 2; ++mh)
#pragma unroll
    for (int r = 0; r < 4; ++r) {
      const float inv = 1.0f / o[mh][8][r];   // l (same value in every lane)
#pragma unroll
      for (int di = 0; di < 8; ++di)
        Ob[wq + mh * 16 + q * 4 + r][di * 16 + l] = f2b(o[mh][di][r] * inv);
    }
  __syncthreads();
  {
    const int row = tid >> 1, g = (tid & 1) * 64;
    const int s = t * 128 + row;
    unsigned short* dst = attn + ((long)(b * SEQ + s)) * (NH * HD) + h * HD + g;
#pragma unroll
    for (int j = 0; j < 8; ++j)
      *(short8*)(dst + j * 8) = *(const short8*)&Ob[row][g + j * 8];
  }
}

// ---------------------------------------------------------------------------
extern "C" void kernel_launch(void* const* d_in, const int* in_sizes, int n_in,
                              void* d_out, int out_size, void* d_ws, size_t ws_size,
                              hipStream_t stream) {
  const float* x       = (const float*)d_in[0];   // [2,2048,2048]
  const float* w_qkv   = (const float*)d_in[1];   // [2048,3072]
  const float* w_dense = (const float*)d_in[2];   // [2048,2048]
  float* out = (float*)d_out;                     // [2,2048,2048] fp32

  char* ws = (char*)d_ws;
  const size_t MB = 1024 * 1024;
  unsigned short* xb    = (unsigned short*)(ws);            // 16 MB (aliased as attn later)
  unsigned short* wqkvT = (unsigned short*)(ws + 16 * MB);  // 12 MB
  unsigned short* wdT   = (unsigned short*)(ws + 28 * MB);  //  8 MB
  unsigned short* Qb    = (unsigned short*)(ws + 36 * MB);  // 16 MB
  unsigned short* Kb    = (unsigned short*)(ws + 52 * MB);  //  4 MB
  unsigned short* VTb   = (unsigned short*)(ws + 56 * MB);  //  4 MB   (total 60 MB)
  unsigned short* attn  = xb;   // x no longer needed after qkv GEMM

  static bool attr_set = false;
  if (!attr_set) {
    (void)hipFuncSetAttribute(reinterpret_cast<const void*>(&gemm_bt<0>),
                              hipFuncAttributeMaxDynamicSharedMemorySize, 131072);
    (void)hipFuncSetAttribute(reinterpret_cast<const void*>(&gemm_bt<1>),
                              hipFuncAttributeMaxDynamicSharedMemorySize, 131072);
    attr_set = true;
  }

  const float qscale = 0.08838834764831845f * 1.4426950408889634f; // 1/sqrt(128)*log2e

  cvt_f32_bf16<<<(MROWS * EMB) / (256 * 4), 256, 0, stream>>>(x, xb, MROWS * EMB);
  transpose_cvt_dual<<<dim3(NQKV / 32, EMB / 32, 2), 256, 0, stream>>>(
      w_qkv, wqkvT, w_dense, wdT);

  gemm_bt<0><<<dim3(NQKV / 256, MROWS / 256), 512, 131072, stream>>>(
      xb, wqkvT, MROWS, NQKV, EMB, nullptr, Qb, Kb, VTb);

  rope_kernel<<<(NBATCH * (NH + NKV) * SEQ * 64) / 256, 256, 0, stream>>>(Qb, Kb, qscale);

  attn_kernel<<<dim3(16, NH, NBATCH), 256, 0, stream>>>(Qb, Kb, VTb, attn);

  gemm_bt<1><<<dim3(EMB / 256, MROWS / 256), 512, 131072, stream>>>(
      attn, wdT, MROWS, EMB, NH * HD, out, nullptr, nullptr, nullptr);
}

// Round 4
// 282.096 us; speedup vs baseline: 1.0362x; 1.0362x over previous
//
#include <hip/hip_runtime.h>
#include <type_traits>

// ---------------------------------------------------------------------------
// MultiHeadAttention fused pipeline for MI355X (gfx950)
// x[B,S,E] @ w_qkv -> split QKV -> RoPE -> causal GQA flash attention -> @ w_dense
// B=2 S=2048 E=2048 H=16 KVH=4 D=128
// R12: revert to R10's proven 128-tile 2-barrier GEMM (853 TF QKV). R11's
//      256x256 8-phase port starved the grid (192/128 blocks on 256 CUs) and
//      regressed. R10 counters show throughput ~ resident blocks (QKV 3/CU =
//      853 TF vs dense 2/CU = 569 TF), so:
//      (a) dense GEMM -> 128x64 tiles: 1024 blocks = 4 blocks/CU, 16 waves/CU.
//      (b) RoPE fused into the QKV GEMM Q/K repack epilogue (tile already in
//          LDS; saves 24MB write + 24MB read + a launch). Bit-identical math.
// R10: attn register-resident P via kv-permuted VT (see attn comment).
// ---------------------------------------------------------------------------

typedef __attribute__((ext_vector_type(8))) short short8;
typedef __attribute__((ext_vector_type(4))) float floatx4;
typedef __attribute__((ext_vector_type(4))) unsigned short ushort4v;
typedef __attribute__((ext_vector_type(4))) unsigned int uint4v;

constexpr int NH    = 16;
constexpr int NKV   = 4;
constexpr int HD    = 128;
constexpr int SEQ   = 2048;
constexpr int EMB   = 2048;
constexpr int NBATCH = 2;
constexpr int MROWS = NBATCH * SEQ;          // 4096
constexpr int NQKV  = (NH + 2 * NKV) * HD;   // 3072

__device__ __forceinline__ unsigned short f2b(float f) {
  union { float f; unsigned u; } v; v.f = f;
  unsigned u = v.u + 0x7FFFu + ((v.u >> 16) & 1u);   // RNE
  return (unsigned short)(u >> 16);
}
__device__ __forceinline__ float b2f(unsigned short h) {
  union { unsigned u; float f; } v; v.u = (unsigned)h << 16;
  return v.f;
}

// async global->LDS DMA, 16B per lane; lds dest = uniform base + lane*16
__device__ __forceinline__ void gload_lds16(const unsigned short* g,
                                            unsigned short* lds) {
  __builtin_amdgcn_global_load_lds(
      (const __attribute__((address_space(1))) unsigned int*)g,
      (__attribute__((address_space(3))) unsigned int*)lds, 16, 0, 0);
}

// --------------------------- fp32 -> bf16 cast ------------------------------
__global__ void cvt_f32_bf16(const float* __restrict__ in,
                             unsigned short* __restrict__ out, int n) {
  int i = (blockIdx.x * 256 + threadIdx.x) * 4;
  if (i + 3 < n) {
    floatx4 v = *(const floatx4*)(in + i);
    ushort4v o = { f2b(v[0]), f2b(v[1]), f2b(v[2]), f2b(v[3]) };
    *(ushort4v*)(out + i) = o;
  }
}

// ---------- fp32 [R][C] -> bf16 [C][R] transpose, both weights in one -------
__global__ void transpose_cvt_dual(const float* __restrict__ wqkv,
                                   unsigned short* __restrict__ oqkv,
                                   const float* __restrict__ wd,
                                   unsigned short* __restrict__ od) {
  const int z = blockIdx.z;
  const float* in = z ? wd : wqkv;
  unsigned short* out = z ? od : oqkv;
  const int R = EMB;                       // both weights have 2048 rows
  const int C = z ? EMB : NQKV;
  int c0 = blockIdx.x * 32, r0 = blockIdx.y * 32;
  if (c0 >= C) return;
  __shared__ float t[32][33];
  int tx = threadIdx.x & 31, ty = threadIdx.x >> 5;  // ty 0..7
#pragma unroll
  for (int i = 0; i < 32; i += 8)
    t[ty + i][tx] = in[(long)(r0 + ty + i) * C + (c0 + tx)];
  __syncthreads();
#pragma unroll
  for (int i = 0; i < 32; i += 8)
    out[(long)(c0 + ty + i) * R + (r0 + tx)] = f2b(t[tx][ty + i]);
}

// ------------------------------- GEMM (B^T) ---------------------------------
// C[M][N] = A[M][K](bf16) * BT[N][K](bf16)^T.  BM=128 tile, 4 waves.
// Unpadded LDS with XOR-swizzled 16B blocks (conflict-free fragment reads),
// global_load_lds width-16 staging.
// MODE 0: BN=128, 3 blocks/CU. Q/K tiles -> LDS repack + FUSED ROPE epilogue,
//         bf16 16B stores head-major; V tiles -> transposed kv-permuted stores.
// MODE 1: BN=64, 4 blocks/CU (1024 blocks). fp32 dense store to outF.
constexpr int BM = 128, BK = 64;

template <int MODE>
__global__ __launch_bounds__(256, MODE == 1 ? 4 : 3) void gemm_bt(
    const unsigned short* __restrict__ A,
    const unsigned short* __restrict__ BT,
    int Mdim, int Ndim, int Kdim,
    float* __restrict__ outF,
    unsigned short* __restrict__ Qb,
    unsigned short* __restrict__ Kb,
    unsigned short* __restrict__ Vt,
    float qscale) {
  constexpr int TBN = (MODE == 1) ? 64 : 128;     // tile N
  constexpr int NI  = TBN / 32;                   // 16-col frags per wave
  __shared__ __align__(16) unsigned short smem[BM * BK + TBN * BK];
  unsigned short (*As)[BK] = (unsigned short (*)[BK])smem;
  unsigned short (*Bs)[BK] = (unsigned short (*)[BK])(smem + BM * BK);
  const int tid = threadIdx.x;
  const int bm = blockIdx.y * BM;
  const int bn = blockIdx.x * TBN;
  const int wave = tid >> 6, lane = tid & 63;
  const int l = lane & 15, q = lane >> 4;
  const int l7 = l & 7;
  const int wm = (wave >> 1) * 64, wn = (wave & 1) * (TBN / 2);

  floatx4 acc[4][NI] = {};

  // DMA staging: one issue = 64 lanes x 16B = 1KB = 8 rows of 64 shorts.
  // Lane (srow=lane>>3, bp=lane&7) lands at phys block bp of row srow;
  // it FETCHES logical block bp^srow, so logical bl sits at phys bl^(row&7).
  const int srow = lane >> 3;                    // 0..7
  const int scol = ((lane & 7) ^ srow) * 8;      // swizzled source col (shorts)
  const unsigned short* Arow = A + (long)bm * Kdim;
  const unsigned short* Brow = BT + (long)bn * Kdim;

  for (int k0 = 0; k0 < Kdim; k0 += BK) {
#pragma unroll
    for (int i = 0; i < 4; ++i) {
      const int r0 = wave * 32 + i * 8;
      gload_lds16(Arow + (long)(r0 + srow) * Kdim + k0 + scol, &As[r0][0]);
    }
#pragma unroll
    for (int i = 0; i < TBN / 32; ++i) {
      const int r0 = wave * (TBN / 4) + i * 8;
      gload_lds16(Brow + (long)(r0 + srow) * Kdim + k0 + scol, &Bs[r0][0]);
    }
    __syncthreads();
#pragma unroll
    for (int kk = 0; kk < 2; ++kk) {
      short8 af[4], bfr[NI];
#pragma unroll
      for (int mi = 0; mi < 4; ++mi)
        af[mi] = *(const short8*)&As[wm + mi * 16 + l][((kk * 4 + q) ^ l7) * 8];
#pragma unroll
      for (int ni = 0; ni < NI; ++ni)
        bfr[ni] = *(const short8*)&Bs[wn + ni * 16 + l][((kk * 4 + q) ^ l7) * 8];
#pragma unroll
      for (int mi = 0; mi < 4; ++mi)
#pragma unroll
        for (int ni = 0; ni < NI; ++ni)
          acc[mi][ni] = __builtin_amdgcn_mfma_f32_16x16x32_bf16(
              af[mi], bfr[ni], acc[mi][ni], 0, 0, 0);
    }
    __syncthreads();
  }

  if constexpr (MODE == 1) {
#pragma unroll
    for (int mi = 0; mi < 4; ++mi) {
      const int rowbase = bm + wm + mi * 16 + q * 4;
#pragma unroll
      for (int ni = 0; ni < NI; ++ni) {
        const int col = bn + wn + ni * 16 + l;
#pragma unroll
        for (int r = 0; r < 4; ++r)
          outF[(long)(rowbase + r) * Ndim + col] = acc[mi][ni][r];
      }
    }
  } else if (bn >= (NH + NKV) * HD) {
    // ---- V tile: transposed stores, kv-permuted within each 64-s chunk ----
    // s%64 bits [5]=c2 [4]=u [3:2]=qq [1:0]=r  ->  p = [5]=c2 [4:3]=qq [2]=u [1:0]=r
    // so that attn's PV A-fragment (lane q holds kv-slots 8q..8q+7 = its own
    // QK accumulators ni=2c2+u, r) matches the B-fragment read from VT.
    const int hh = (bn - (NH + NKV) * HD) >> 7;
#pragma unroll
    for (int mi = 0; mi < 4; ++mi) {
      const int m0 = bm + wm + mi * 16 + q * 4;
      const int bb = m0 >> 11, s = m0 & (SEQ - 1);
      const int s6 = s & 63;                 // bits[1:0]=0 (q*4 aligned)
      const int p6 = (s6 & 32) | ((s6 & 12) << 1) | ((s6 & 16) >> 2);
      const int sp = (s & ~63) | p6;
      unsigned short* vtb = Vt + ((long)(bb * NKV + hh)) * HD * SEQ;
#pragma unroll
      for (int ni = 0; ni < NI; ++ni) {
        const int d = wn + ni * 16 + l;        // TBN == HD
        ushort4v pv = { f2b(acc[mi][ni][0]), f2b(acc[mi][ni][1]),
                        f2b(acc[mi][ni][2]), f2b(acc[mi][ni][3]) };
        *(ushort4v*)(vtb + (long)d * SEQ + sp) = pv;
      }
    }
  } else {
    // ---- Q/K tiles: repack through LDS + FUSED ROPE ----
    // Ct[128][128] bf16, 16B-block col swizzle: blk_phys = (lb&8)|((lb^row)&7).
    unsigned short (*Ct)[128] = (unsigned short (*)[128])smem;
#pragma unroll
    for (int mi = 0; mi < 4; ++mi)
#pragma unroll
      for (int ni = 0; ni < NI; ++ni)
#pragma unroll
        for (int r = 0; r < 4; ++r) {
          const int row = wm + mi * 16 + q * 4 + r;
          const int col = wn + ni * 16 + l;
          const int cs = ((((col >> 3) ^ row) & 7) | (col & 64 ? 8 : 0)) * 8 + (col & 7);
          Ct[row][cs] = f2b(acc[mi][ni][r]);
        }
    __syncthreads();
    // Each thread: one row-half (64 outputs). Rope pairs (j, j+64) span both
    // halves -> read own + other logical half, rotate, scale, store.
    const int row = tid >> 1, g = tid & 1;
    const int m = bm + row, bb = m >> 11, s = m & (SEQ - 1);
    const bool isQ = (bn < NH * HD);
    unsigned short* dst;
    if (isQ) dst = Qb + (((long)(bb * NH + (bn >> 7))) * SEQ + s) * HD;
    else     dst = Kb + (((long)(bb * NKV + ((bn - NH * HD) >> 7))) * SEQ + s) * HD;
    const float scale = isQ ? qscale : 1.0f;
    const float sf = (float)s;
#pragma unroll
    for (int i = 0; i < 8; ++i) {
      const int lbo = g * 8 + i;                  // own logical 16B block
      const int lbx = (g ^ 1) * 8 + i;            // other-half logical block
      const int pbo = (lbo & 8) | ((lbo ^ row) & 7);
      const int pbx = (lbx & 8) | ((lbx ^ row) & 7);
      short8 xo = *(const short8*)&Ct[row][pbo * 8];
      short8 xx = *(const short8*)&Ct[row][pbx * 8];
      short8 outv;
#pragma unroll
      for (int j2 = 0; j2 < 8; ++j2) {
        const int j = i * 8 + j2;                 // rotary index 0..63
        const float e = -(float)j * (2.0f * 13.287712379549449f / 128.0f);
        const float ang = sf * exp2f(e);
        float sn, cs_;
        sincosf(ang, &sn, &cs_);
        const float xown = b2f((unsigned short)xo[j2]);
        const float xoth = b2f((unsigned short)xx[j2]);
        const float rr = g ? (xown * cs_ + xoth * sn)
                           : (xown * cs_ - xoth * sn);
        outv[j2] = (short)f2b(rr * scale);
      }
      *(short8*)(dst + g * 64 + i * 8) = outv;
    }
  }
}

// --------------------------- flash attention --------------------------------
// R10 structure: 128-row q-tiles, 4 waves x 32 q-rows (2 mh sub-tiles of 16).
// Swapped QK^T (sf = mfma(K,Q)) -> lane holds P[kv=ni*16+q*4+r][qrow=l].
// P stays in registers: cvt_pk pairs -> 4 u32 = short8 = PV A-fragment under
// the kv-permutation baked into VT's global layout (see gemm V-epilogue).
// LDS: Ks 32K + VTs 32K = 64KB -> 2 blocks/CU.
// Grid (16,16,2); t = b ? 15-bx : bx so the two co-resident blocks per CU
// (linear ids i, i+256) carry complementary tiles -> uniform 34 chunks/CU.
__global__ __launch_bounds__(256, 2) void attn_kernel(
    const unsigned short* __restrict__ Q,   // [B][NH][S][D], pre-scaled by 1/sqrt(d)*log2e
    const unsigned short* __restrict__ K,   // [B][NKV][S][D]
    const unsigned short* __restrict__ VT,  // [B][NKV][D][S], kv-permuted per 64
    unsigned short* __restrict__ attn) {    // [B*S][NH*D]
  const int h = blockIdx.y, b = blockIdx.z;
  const int t = b ? (15 - (int)blockIdx.x) : (int)blockIdx.x;  // q-tile (128 rows)
  const int kvh = h >> 2;   // jnp.repeat: q head h uses kv head h/4
  const int tid = threadIdx.x;
  const int wave = tid >> 6, lane = tid & 63;
  const int l = lane & 15, q = lane >> 4;
  const int l7 = l & 7;
  const int wq = wave * 32;

  const unsigned short* Kh  = K  + ((long)(b * NKV + kvh)) * SEQ * HD;
  const unsigned short* VTh = VT + ((long)(b * NKV + kvh)) * HD * SEQ;

  __shared__ __align__(16) unsigned short smem[2 * 64 * 128 + 2 * 128 * 64]; // 64 KB
  unsigned short (*Ks)[64 * 128]  = (unsigned short (*)[64 * 128])smem;
  unsigned short (*VTs)[128 * 64] = (unsigned short (*)[128 * 64])(smem + 2 * 64 * 128);

  int koff[4], voff[4];
  {
    const int k_rl = lane >> 4, k_bp = lane & 15;
    const int v_rl = lane >> 3, v_bp = lane & 7;
#pragma unroll
    for (int j = 0; j < 4; ++j) {
      const int rk = (wave * 4 + j) * 4 + k_rl;
      koff[j] = rk * HD + (k_bp ^ (rk & 15)) * 8;
      const int rv = (wave * 4 + j) * 8 + v_rl;
      voff[j] = rv * SEQ + (v_bp ^ (rv & 7)) * 8;
    }
  }

  short8 onesf;
#pragma unroll
  for (int i = 0; i < 8; ++i) onesf[i] = (short)0x3F80;   // bf16 1.0

  auto stage = [&](int c, int buf) {
    const unsigned short* kc = Kh + c * (64 * HD);
    const unsigned short* vc = VTh + c * 64;
#pragma unroll
    for (int j = 0; j < 4; ++j)
      gload_lds16(kc + koff[j], &Ks[buf][(wave * 4 + j) * 4 * 128]);
#pragma unroll
    for (int j = 0; j < 4; ++j)
      gload_lds16(vc + voff[j], &VTs[buf][(wave * 4 + j) * 8 * 64]);
  };

  const unsigned short* Qh = Q + (((long)(b * NH + h)) * SEQ + t * 128) * HD;
  short8 qf[2][4];
#pragma unroll
  for (int mh = 0; mh < 2; ++mh)
#pragma unroll
    for (int kk = 0; kk < 4; ++kk)
      qf[mh][kk] = *(const short8*)(Qh + (long)(wq + mh * 16 + l) * HD + kk * 32 + q * 8);

  floatx4 o[2][9] = {};   // [mh][0..7]=O d-tiles, [8]=denominator (ones col)

  auto chunk_body = [&](auto masked, int cur, int kv0) {
    constexpr bool MASKED = decltype(masked)::value;
    floatx4 sf[2][4] = {};
#pragma unroll
    for (int kk = 0; kk < 4; ++kk) {
      short8 kf[4];
#pragma unroll
      for (int ni = 0; ni < 4; ++ni)
        kf[ni] = *(const short8*)&Ks[cur][(ni * 16 + l) * 128 + (((kk * 4 + q) ^ l) * 8)];
#pragma unroll
      for (int mh = 0; mh < 2; ++mh)
#pragma unroll
        for (int ni = 0; ni < 4; ++ni)
          sf[mh][ni] = __builtin_amdgcn_mfma_f32_16x16x32_bf16(
              kf[ni], qf[mh][kk], sf[mh][ni], 0, 0, 0);
    }
    short8 pf[2][2];
#pragma unroll
    for (int mh = 0; mh < 2; ++mh) {
      const int qrow = t * 128 + wq + mh * 16 + l;
      unsigned u[8];
#pragma unroll
      for (int ni = 0; ni < 4; ++ni) {
        if constexpr (MASKED) {
#pragma unroll
          for (int r = 0; r < 4; ++r)
            if (kv0 + ni * 16 + q * 4 + r > qrow) sf[mh][ni][r] = -3e38f;  // exp2 -> 0
        }
        float e0 = exp2f(sf[mh][ni][0]);
        float e1 = exp2f(sf[mh][ni][1]);
        float e2 = exp2f(sf[mh][ni][2]);
        float e3 = exp2f(sf[mh][ni][3]);
        asm("v_cvt_pk_bf16_f32 %0, %1, %2" : "=v"(u[ni * 2]) : "v"(e0), "v"(e1));
        asm("v_cvt_pk_bf16_f32 %0, %1, %2" : "=v"(u[ni * 2 + 1]) : "v"(e2), "v"(e3));
      }
      union { uint4v v; short8 s; } a0, a1;
      a0.v = (uint4v){u[0], u[1], u[2], u[3]};
      a1.v = (uint4v){u[4], u[5], u[6], u[7]};
      pf[mh][0] = a0.s;   // kv-slots: pi(8q+j) = q*4+(j&3) + (j>=4)*16
      pf[mh][1] = a1.s;   // + 32
    }
#pragma unroll
    for (int c2 = 0; c2 < 2; ++c2) {
      const int pb = ((c2 * 4 + q) ^ l7) * 8;
#pragma unroll
      for (int di = 0; di < 8; ++di) {
        short8 vf = *(const short8*)&VTs[cur][(di * 16 + l) * 64 + pb];
        o[0][di] = __builtin_amdgcn_mfma_f32_16x16x32_bf16(pf[0][c2], vf, o[0][di], 0, 0, 0);
        o[1][di] = __builtin_amdgcn_mfma_f32_16x16x32_bf16(pf[1][c2], vf, o[1][di], 0, 0, 0);
      }
      o[0][8] = __builtin_amdgcn_mfma_f32_16x16x32_bf16(pf[0][c2], onesf, o[0][8], 0, 0, 0);
      o[1][8] = __builtin_amdgcn_mfma_f32_16x16x32_bf16(pf[1][c2], onesf, o[1][8], 0, 0, 0);
    }
  };

  const int nc = 2 * t + 2;   // causal: kv up to 128t+127, Tk=64
  stage(0, 0);
  __syncthreads();

  int c = 0;
#pragma unroll 1
  for (; c < nc - 2; ++c) {
    stage(c + 1, (c & 1) ^ 1);
    chunk_body(std::false_type{}, c & 1, c * 64);
    __syncthreads();   // prefetch DMA drained; all reads of cur done
  }
  stage(c + 1, (c & 1) ^ 1);
  chunk_body(std::true_type{}, c & 1, c * 64);
  __syncthreads();
  ++c;
  chunk_body(std::true_type{}, c & 1, c * 64);
  __syncthreads();     // all waves done reading Ks/VTs before repack overwrite

  unsigned short (*Ob)[136] = (unsigned short (*)[136])smem;  // 34.8 KB < 64 KB
#pragma unroll
  for (int mh = 0; mh < 2; ++mh)
#pragma unroll
    for (int r = 0; r < 4; ++r) {
      const float inv = 1.0f / o[mh][8][r];   // l (same value in every lane)
#pragma unroll
      for (int di = 0; di < 8; ++di)
        Ob[wq + mh * 16 + q * 4 + r][di * 16 + l] = f2b(o[mh][di][r] * inv);
    }
  __syncthreads();
  {
    const int row = tid >> 1, g = (tid & 1) * 64;
    const int s = t * 128 + row;
    unsigned short* dst = attn + ((long)(b * SEQ + s)) * (NH * HD) + h * HD + g;
#pragma unroll
    for (int j = 0; j < 8; ++j)
      *(short8*)(dst + j * 8) = *(const short8*)&Ob[row][g + j * 8];
  }
}

// ---------------------------------------------------------------------------
extern "C" void kernel_launch(void* const* d_in, const int* in_sizes, int n_in,
                              void* d_out, int out_size, void* d_ws, size_t ws_size,
                              hipStream_t stream) {
  const float* x       = (const float*)d_in[0];   // [2,2048,2048]
  const float* w_qkv   = (const float*)d_in[1];   // [2048,3072]
  const float* w_dense = (const float*)d_in[2];   // [2048,2048]
  float* out = (float*)d_out;                     // [2,2048,2048] fp32

  char* ws = (char*)d_ws;
  const size_t MB = 1024 * 1024;
  unsigned short* xb    = (unsigned short*)(ws);            // 16 MB (aliased as attn later)
  unsigned short* wqkvT = (unsigned short*)(ws + 16 * MB);  // 12 MB
  unsigned short* wdT   = (unsigned short*)(ws + 28 * MB);  //  8 MB
  unsigned short* Qb    = (unsigned short*)(ws + 36 * MB);  // 16 MB
  unsigned short* Kb    = (unsigned short*)(ws + 52 * MB);  //  4 MB
  unsigned short* VTb   = (unsigned short*)(ws + 56 * MB);  //  4 MB   (total 60 MB)
  unsigned short* attn  = xb;   // x no longer needed after qkv GEMM

  const float qscale = 0.08838834764831845f * 1.4426950408889634f; // 1/sqrt(128)*log2e

  cvt_f32_bf16<<<(MROWS * EMB) / (256 * 4), 256, 0, stream>>>(x, xb, MROWS * EMB);
  transpose_cvt_dual<<<dim3(NQKV / 32, EMB / 32, 2), 256, 0, stream>>>(
      w_qkv, wqkvT, w_dense, wdT);

  // QKV GEMM with fused RoPE in the Q/K epilogue (BN=128, 768 blocks, 3/CU)
  gemm_bt<0><<<dim3(NQKV / 128, MROWS / BM), 256, 0, stream>>>(
      xb, wqkvT, MROWS, NQKV, EMB, nullptr, Qb, Kb, VTb, qscale);

  attn_kernel<<<dim3(16, NH, NBATCH), 256, 0, stream>>>(Qb, Kb, VTb, attn);

  // dense GEMM (BN=64, 1024 blocks, 4/CU)
  gemm_bt<1><<<dim3(EMB / 64, MROWS / BM), 256, 0, stream>>>(
      attn, wdT, MROWS, EMB, NH * HD, out, nullptr, nullptr, nullptr, 0.0f);
}

// Round 5
// 275.338 us; speedup vs baseline: 1.0616x; 1.0245x over previous
//
#include <hip/hip_runtime.h>
#include <type_traits>

// ---------------------------------------------------------------------------
// MultiHeadAttention fused pipeline for MI355X (gfx950)
// x[B,S,E] @ w_qkv -> split QKV -> RoPE -> causal GQA flash attention -> @ w_dense
// B=2 S=2048 E=2048 H=16 KVH=4 D=128
// R13: QKV epilogue fixes (R12 counters: WRITE 51MB = 8x V write amplification;
//      VALUBusy 34% = 64 sincosf/thread in fused rope).
//      (a) rope trig table precomputed by a 1us kernel (bit-identical values);
//          Q/K epilogue loads (cos,sin) f32 pairs from L2 instead of sincosf.
//      (b) V epilogue repacks through swizzled Ct[s][d] LDS then stores 128B
//          contiguous permuted runs of VT[d][.] (inverse kv-permutation on the
//          LDS gather) -> full cachelines, no amplification.
// R12: dense GEMM BN=64 (1024 blocks, 4/CU); rope fused into QKV epilogue.
// R10: attn register-resident P via kv-permuted VT (see attn comment).
// ---------------------------------------------------------------------------

typedef __attribute__((ext_vector_type(8))) short short8;
typedef __attribute__((ext_vector_type(4))) float floatx4;
typedef __attribute__((ext_vector_type(4))) unsigned short ushort4v;
typedef __attribute__((ext_vector_type(4))) unsigned int uint4v;

constexpr int NH    = 16;
constexpr int NKV   = 4;
constexpr int HD    = 128;
constexpr int SEQ   = 2048;
constexpr int EMB   = 2048;
constexpr int NBATCH = 2;
constexpr int MROWS = NBATCH * SEQ;          // 4096
constexpr int NQKV  = (NH + 2 * NKV) * HD;   // 3072

__device__ __forceinline__ unsigned short f2b(float f) {
  union { float f; unsigned u; } v; v.f = f;
  unsigned u = v.u + 0x7FFFu + ((v.u >> 16) & 1u);   // RNE
  return (unsigned short)(u >> 16);
}
__device__ __forceinline__ float b2f(unsigned short h) {
  union { unsigned u; float f; } v; v.u = (unsigned)h << 16;
  return v.f;
}

// async global->LDS DMA, 16B per lane; lds dest = uniform base + lane*16
__device__ __forceinline__ void gload_lds16(const unsigned short* g,
                                            unsigned short* lds) {
  __builtin_amdgcn_global_load_lds(
      (const __attribute__((address_space(1))) unsigned int*)g,
      (__attribute__((address_space(3))) unsigned int*)lds, 16, 0, 0);
}

// --------------------------- fp32 -> bf16 cast ------------------------------
__global__ void cvt_f32_bf16(const float* __restrict__ in,
                             unsigned short* __restrict__ out, int n) {
  int i = (blockIdx.x * 256 + threadIdx.x) * 4;
  if (i + 3 < n) {
    floatx4 v = *(const floatx4*)(in + i);
    ushort4v o = { f2b(v[0]), f2b(v[1]), f2b(v[2]), f2b(v[3]) };
    *(ushort4v*)(out + i) = o;
  }
}

// --------------------- RoPE (cos,sin) table [SEQ][64] -----------------------
// Same float expressions as the old rope_kernel -> bit-identical results.
__global__ void rope_table(float* __restrict__ tab) {
  int idx = blockIdx.x * 256 + threadIdx.x;   // 0..SEQ*64-1
  int j = idx & 63, s = idx >> 6;
  float e = -(float)j * (2.0f * 13.287712379549449f / 128.0f);
  float ang = (float)s * exp2f(e);
  float sn, c;
  sincosf(ang, &sn, &c);
  tab[idx * 2]     = c;
  tab[idx * 2 + 1] = sn;
}

// ---------- fp32 [R][C] -> bf16 [C][R] transpose, both weights in one -------
__global__ void transpose_cvt_dual(const float* __restrict__ wqkv,
                                   unsigned short* __restrict__ oqkv,
                                   const float* __restrict__ wd,
                                   unsigned short* __restrict__ od) {
  const int z = blockIdx.z;
  const float* in = z ? wd : wqkv;
  unsigned short* out = z ? od : oqkv;
  const int R = EMB;                       // both weights have 2048 rows
  const int C = z ? EMB : NQKV;
  int c0 = blockIdx.x * 32, r0 = blockIdx.y * 32;
  if (c0 >= C) return;
  __shared__ float t[32][33];
  int tx = threadIdx.x & 31, ty = threadIdx.x >> 5;  // ty 0..7
#pragma unroll
  for (int i = 0; i < 32; i += 8)
    t[ty + i][tx] = in[(long)(r0 + ty + i) * C + (c0 + tx)];
  __syncthreads();
#pragma unroll
  for (int i = 0; i < 32; i += 8)
    out[(long)(c0 + ty + i) * R + (r0 + tx)] = f2b(t[tx][ty + i]);
}

// ------------------------------- GEMM (B^T) ---------------------------------
// C[M][N] = A[M][K](bf16) * BT[N][K](bf16)^T.  BM=128 tile, 4 waves.
// Unpadded LDS with XOR-swizzled 16B blocks (conflict-free fragment reads),
// global_load_lds width-16 staging.
// MODE 0: BN=128, 3 blocks/CU. Q/K tiles -> LDS repack + table-driven RoPE,
//         16B head-major stores; V tiles -> LDS repack + 128B permuted stores.
// MODE 1: BN=64, 4 blocks/CU (1024 blocks). fp32 dense store to outF.
constexpr int BM = 128, BK = 64;

template <int MODE>
__global__ __launch_bounds__(256, MODE == 1 ? 4 : 3) void gemm_bt(
    const unsigned short* __restrict__ A,
    const unsigned short* __restrict__ BT,
    int Mdim, int Ndim, int Kdim,
    float* __restrict__ outF,
    unsigned short* __restrict__ Qb,
    unsigned short* __restrict__ Kb,
    unsigned short* __restrict__ Vt,
    const float* __restrict__ ropetab,
    float qscale) {
  constexpr int TBN = (MODE == 1) ? 64 : 128;     // tile N
  constexpr int NI  = TBN / 32;                   // 16-col frags per wave
  __shared__ __align__(16) unsigned short smem[BM * BK + TBN * BK];
  unsigned short (*As)[BK] = (unsigned short (*)[BK])smem;
  unsigned short (*Bs)[BK] = (unsigned short (*)[BK])(smem + BM * BK);
  const int tid = threadIdx.x;
  const int bm = blockIdx.y * BM;
  const int bn = blockIdx.x * TBN;
  const int wave = tid >> 6, lane = tid & 63;
  const int l = lane & 15, q = lane >> 4;
  const int l7 = l & 7;
  const int wm = (wave >> 1) * 64, wn = (wave & 1) * (TBN / 2);

  floatx4 acc[4][NI] = {};

  // DMA staging: one issue = 64 lanes x 16B = 1KB = 8 rows of 64 shorts.
  // Lane (srow=lane>>3, bp=lane&7) lands at phys block bp of row srow;
  // it FETCHES logical block bp^srow, so logical bl sits at phys bl^(row&7).
  const int srow = lane >> 3;                    // 0..7
  const int scol = ((lane & 7) ^ srow) * 8;      // swizzled source col (shorts)
  const unsigned short* Arow = A + (long)bm * Kdim;
  const unsigned short* Brow = BT + (long)bn * Kdim;

  for (int k0 = 0; k0 < Kdim; k0 += BK) {
#pragma unroll
    for (int i = 0; i < 4; ++i) {
      const int r0 = wave * 32 + i * 8;
      gload_lds16(Arow + (long)(r0 + srow) * Kdim + k0 + scol, &As[r0][0]);
    }
#pragma unroll
    for (int i = 0; i < TBN / 32; ++i) {
      const int r0 = wave * (TBN / 4) + i * 8;
      gload_lds16(Brow + (long)(r0 + srow) * Kdim + k0 + scol, &Bs[r0][0]);
    }
    __syncthreads();
#pragma unroll
    for (int kk = 0; kk < 2; ++kk) {
      short8 af[4], bfr[NI];
#pragma unroll
      for (int mi = 0; mi < 4; ++mi)
        af[mi] = *(const short8*)&As[wm + mi * 16 + l][((kk * 4 + q) ^ l7) * 8];
#pragma unroll
      for (int ni = 0; ni < NI; ++ni)
        bfr[ni] = *(const short8*)&Bs[wn + ni * 16 + l][((kk * 4 + q) ^ l7) * 8];
#pragma unroll
      for (int mi = 0; mi < 4; ++mi)
#pragma unroll
        for (int ni = 0; ni < NI; ++ni)
          acc[mi][ni] = __builtin_amdgcn_mfma_f32_16x16x32_bf16(
              af[mi], bfr[ni], acc[mi][ni], 0, 0, 0);
    }
    __syncthreads();
  }

  if constexpr (MODE == 1) {
#pragma unroll
    for (int mi = 0; mi < 4; ++mi) {
      const int rowbase = bm + wm + mi * 16 + q * 4;
#pragma unroll
      for (int ni = 0; ni < NI; ++ni) {
        const int col = bn + wn + ni * 16 + l;
#pragma unroll
        for (int r = 0; r < 4; ++r)
          outF[(long)(rowbase + r) * Ndim + col] = acc[mi][ni][r];
      }
    }
    return;
  }

  // ---- MODE 0 epilogues: all repack through swizzled Ct[128][128] ----
  // 16B-block col swizzle: blk_phys = (blk & 8) | ((blk ^ row) & 7).
  unsigned short (*Ct)[128] = (unsigned short (*)[128])smem;
#pragma unroll
  for (int mi = 0; mi < 4; ++mi)
#pragma unroll
    for (int ni = 0; ni < NI; ++ni)
#pragma unroll
      for (int r = 0; r < 4; ++r) {
        const int row = wm + mi * 16 + q * 4 + r;
        const int col = wn + ni * 16 + l;
        const int cs = ((((col >> 3) ^ row) & 7) | (col & 64 ? 8 : 0)) * 8 + (col & 7);
        Ct[row][cs] = f2b(acc[mi][ni][r]);
      }
  __syncthreads();

  if (bn >= (NH + NKV) * HD) {
    // ---- V tile: 128B contiguous permuted stores into VT[d][s] ----
    // attn needs VT[d][(s&~63)|p6] where p6 bits [5]=c2 [4:3]=qq [2]=u [1:0]=r
    // of s6 bits [5]=c2 [4]=u [3:2]=qq [1:0]=r. Gather with the inverse:
    // s6 = (p6&32) | ((p6&24)>>1) | ((p6&4)<<2) | (p6&3).
    const int hh = (bn - (NH + NKV) * HD) >> 7;
    const int d = tid >> 1, ch = tid & 1;        // d 0..127, s-chunk half
    const int m0 = bm + ch * 64;
    const int bb = m0 >> 11, sbase = m0 & (SEQ - 1);
    unsigned short* vrow =
        Vt + ((long)(bb * NKV + hh)) * HD * SEQ + (long)d * SEQ + sbase;
    const int dblk = d >> 3, dlo = d & 7, dhi = (d & 64) ? 8 : 0;
#pragma unroll
    for (int pb = 0; pb < 8; ++pb) {             // 8 x 16B stores = 128B
      short8 ov;
#pragma unroll
      for (int j = 0; j < 8; ++j) {
        const int p6 = pb * 8 + j;
        const int s6 = (p6 & 32) | ((p6 & 24) >> 1) | ((p6 & 4) << 2) | (p6 & 3);
        const int row = ch * 64 + s6;
        const int cs = (((dblk ^ row) & 7) | dhi) * 8 + dlo;
        ov[j] = (short)Ct[row][cs];
      }
      *(short8*)(vrow + pb * 8) = ov;
    }
  } else {
    // ---- Q/K tiles: table-driven RoPE + 16B head-major stores ----
    const int row = tid >> 1, g = tid & 1;
    const int m = bm + row, bb = m >> 11, s = m & (SEQ - 1);
    const bool isQ = (bn < NH * HD);
    unsigned short* dst;
    if (isQ) dst = Qb + (((long)(bb * NH + (bn >> 7))) * SEQ + s) * HD;
    else     dst = Kb + (((long)(bb * NKV + ((bn - NH * HD) >> 7))) * SEQ + s) * HD;
    const float scale = isQ ? qscale : 1.0f;
    const float* trow = ropetab + (long)s * 128;   // 64 (cos,sin) pairs
#pragma unroll
    for (int i = 0; i < 8; ++i) {
      const int lbo = g * 8 + i;                  // own logical 16B block
      const int lbx = (g ^ 1) * 8 + i;            // other-half logical block
      const int pbo = (lbo & 8) | ((lbo ^ row) & 7);
      const int pbx = (lbx & 8) | ((lbx ^ row) & 7);
      short8 xo = *(const short8*)&Ct[row][pbo * 8];
      short8 xx = *(const short8*)&Ct[row][pbx * 8];
      floatx4 t0 = *(const floatx4*)(trow + i * 16);
      floatx4 t1 = *(const floatx4*)(trow + i * 16 + 4);
      floatx4 t2 = *(const floatx4*)(trow + i * 16 + 8);
      floatx4 t3 = *(const floatx4*)(trow + i * 16 + 12);
      const float cc[8] = { t0[0], t0[2], t1[0], t1[2], t2[0], t2[2], t3[0], t3[2] };
      const float ss[8] = { t0[1], t0[3], t1[1], t1[3], t2[1], t2[3], t3[1], t3[3] };
      short8 outv;
#pragma unroll
      for (int j2 = 0; j2 < 8; ++j2) {
        const float xown = b2f((unsigned short)xo[j2]);
        const float xoth = b2f((unsigned short)xx[j2]);
        const float rr = g ? (xown * cc[j2] + xoth * ss[j2])
                           : (xown * cc[j2] - xoth * ss[j2]);
        outv[j2] = (short)f2b(rr * scale);
      }
      *(short8*)(dst + g * 64 + i * 8) = outv;
    }
  }
}

// --------------------------- flash attention --------------------------------
// R10 structure: 128-row q-tiles, 4 waves x 32 q-rows (2 mh sub-tiles of 16).
// Swapped QK^T (sf = mfma(K,Q)) -> lane holds P[kv=ni*16+q*4+r][qrow=l].
// P stays in registers: cvt_pk pairs -> 4 u32 = short8 = PV A-fragment under
// the kv-permutation baked into VT's global layout (see gemm V-epilogue).
// LDS: Ks 32K + VTs 32K = 64KB -> 2 blocks/CU.
// Grid (16,16,2); t = b ? 15-bx : bx so the two co-resident blocks per CU
// (linear ids i, i+256) carry complementary tiles -> uniform 34 chunks/CU.
__global__ __launch_bounds__(256, 2) void attn_kernel(
    const unsigned short* __restrict__ Q,   // [B][NH][S][D], pre-scaled by 1/sqrt(d)*log2e
    const unsigned short* __restrict__ K,   // [B][NKV][S][D]
    const unsigned short* __restrict__ VT,  // [B][NKV][D][S], kv-permuted per 64
    unsigned short* __restrict__ attn) {    // [B*S][NH*D]
  const int h = blockIdx.y, b = blockIdx.z;
  const int t = b ? (15 - (int)blockIdx.x) : (int)blockIdx.x;  // q-tile (128 rows)
  const int kvh = h >> 2;   // jnp.repeat: q head h uses kv head h/4
  const int tid = threadIdx.x;
  const int wave = tid >> 6, lane = tid & 63;
  const int l = lane & 15, q = lane >> 4;
  const int l7 = l & 7;
  const int wq = wave * 32;

  const unsigned short* Kh  = K  + ((long)(b * NKV + kvh)) * SEQ * HD;
  const unsigned short* VTh = VT + ((long)(b * NKV + kvh)) * HD * SEQ;

  __shared__ __align__(16) unsigned short smem[2 * 64 * 128 + 2 * 128 * 64]; // 64 KB
  unsigned short (*Ks)[64 * 128]  = (unsigned short (*)[64 * 128])smem;
  unsigned short (*VTs)[128 * 64] = (unsigned short (*)[128 * 64])(smem + 2 * 64 * 128);

  int koff[4], voff[4];
  {
    const int k_rl = lane >> 4, k_bp = lane & 15;
    const int v_rl = lane >> 3, v_bp = lane & 7;
#pragma unroll
    for (int j = 0; j < 4; ++j) {
      const int rk = (wave * 4 + j) * 4 + k_rl;
      koff[j] = rk * HD + (k_bp ^ (rk & 15)) * 8;
      const int rv = (wave * 4 + j) * 8 + v_rl;
      voff[j] = rv * SEQ + (v_bp ^ (rv & 7)) * 8;
    }
  }

  short8 onesf;
#pragma unroll
  for (int i = 0; i < 8; ++i) onesf[i] = (short)0x3F80;   // bf16 1.0

  auto stage = [&](int c, int buf) {
    const unsigned short* kc = Kh + c * (64 * HD);
    const unsigned short* vc = VTh + c * 64;
#pragma unroll
    for (int j = 0; j < 4; ++j)
      gload_lds16(kc + koff[j], &Ks[buf][(wave * 4 + j) * 4 * 128]);
#pragma unroll
    for (int j = 0; j < 4; ++j)
      gload_lds16(vc + voff[j], &VTs[buf][(wave * 4 + j) * 8 * 64]);
  };

  const unsigned short* Qh = Q + (((long)(b * NH + h)) * SEQ + t * 128) * HD;
  short8 qf[2][4];
#pragma unroll
  for (int mh = 0; mh < 2; ++mh)
#pragma unroll
    for (int kk = 0; kk < 4; ++kk)
      qf[mh][kk] = *(const short8*)(Qh + (long)(wq + mh * 16 + l) * HD + kk * 32 + q * 8);

  floatx4 o[2][9] = {};   // [mh][0..7]=O d-tiles, [8]=denominator (ones col)

  auto chunk_body = [&](auto masked, int cur, int kv0) {
    constexpr bool MASKED = decltype(masked)::value;
    floatx4 sf[2][4] = {};
#pragma unroll
    for (int kk = 0; kk < 4; ++kk) {
      short8 kf[4];
#pragma unroll
      for (int ni = 0; ni < 4; ++ni)
        kf[ni] = *(const short8*)&Ks[cur][(ni * 16 + l) * 128 + (((kk * 4 + q) ^ l) * 8)];
#pragma unroll
      for (int mh = 0; mh < 2; ++mh)
#pragma unroll
        for (int ni = 0; ni < 4; ++ni)
          sf[mh][ni] = __builtin_amdgcn_mfma_f32_16x16x32_bf16(
              kf[ni], qf[mh][kk], sf[mh][ni], 0, 0, 0);
    }
    short8 pf[2][2];
#pragma unroll
    for (int mh = 0; mh < 2; ++mh) {
      const int qrow = t * 128 + wq + mh * 16 + l;
      unsigned u[8];
#pragma unroll
      for (int ni = 0; ni < 4; ++ni) {
        if constexpr (MASKED) {
#pragma unroll
          for (int r = 0; r < 4; ++r)
            if (kv0 + ni * 16 + q * 4 + r > qrow) sf[mh][ni][r] = -3e38f;  // exp2 -> 0
        }
        float e0 = exp2f(sf[mh][ni][0]);
        float e1 = exp2f(sf[mh][ni][1]);
        float e2 = exp2f(sf[mh][ni][2]);
        float e3 = exp2f(sf[mh][ni][3]);
        asm("v_cvt_pk_bf16_f32 %0, %1, %2" : "=v"(u[ni * 2]) : "v"(e0), "v"(e1));
        asm("v_cvt_pk_bf16_f32 %0, %1, %2" : "=v"(u[ni * 2 + 1]) : "v"(e2), "v"(e3));
      }
      union { uint4v v; short8 s; } a0, a1;
      a0.v = (uint4v){u[0], u[1], u[2], u[3]};
      a1.v = (uint4v){u[4], u[5], u[6], u[7]};
      pf[mh][0] = a0.s;   // kv-slots: pi(8q+j) = q*4+(j&3) + (j>=4)*16
      pf[mh][1] = a1.s;   // + 32
    }
#pragma unroll
    for (int c2 = 0; c2 < 2; ++c2) {
      const int pb = ((c2 * 4 + q) ^ l7) * 8;
#pragma unroll
      for (int di = 0; di < 8; ++di) {
        short8 vf = *(const short8*)&VTs[cur][(di * 16 + l) * 64 + pb];
        o[0][di] = __builtin_amdgcn_mfma_f32_16x16x32_bf16(pf[0][c2], vf, o[0][di], 0, 0, 0);
        o[1][di] = __builtin_amdgcn_mfma_f32_16x16x32_bf16(pf[1][c2], vf, o[1][di], 0, 0, 0);
      }
      o[0][8] = __builtin_amdgcn_mfma_f32_16x16x32_bf16(pf[0][c2], onesf, o[0][8], 0, 0, 0);
      o[1][8] = __builtin_amdgcn_mfma_f32_16x16x32_bf16(pf[1][c2], onesf, o[1][8], 0, 0, 0);
    }
  };

  const int nc = 2 * t + 2;   // causal: kv up to 128t+127, Tk=64
  stage(0, 0);
  __syncthreads();

  int c = 0;
#pragma unroll 1
  for (; c < nc - 2; ++c) {
    stage(c + 1, (c & 1) ^ 1);
    chunk_body(std::false_type{}, c & 1, c * 64);
    __syncthreads();   // prefetch DMA drained; all reads of cur done
  }
  stage(c + 1, (c & 1) ^ 1);
  chunk_body(std::true_type{}, c & 1, c * 64);
  __syncthreads();
  ++c;
  chunk_body(std::true_type{}, c & 1, c * 64);
  __syncthreads();     // all waves done reading Ks/VTs before repack overwrite

  unsigned short (*Ob)[136] = (unsigned short (*)[136])smem;  // 34.8 KB < 64 KB
#pragma unroll
  for (int mh = 0; mh < 2; ++mh)
#pragma unroll
    for (int r = 0; r < 4; ++r) {
      const float inv = 1.0f / o[mh][8][r];   // l (same value in every lane)
#pragma unroll
      for (int di = 0; di < 8; ++di)
        Ob[wq + mh * 16 + q * 4 + r][di * 16 + l] = f2b(o[mh][di][r] * inv);
    }
  __syncthreads();
  {
    const int row = tid >> 1, g = (tid & 1) * 64;
    const int s = t * 128 + row;
    unsigned short* dst = attn + ((long)(b * SEQ + s)) * (NH * HD) + h * HD + g;
#pragma unroll
    for (int j = 0; j < 8; ++j)
      *(short8*)(dst + j * 8) = *(const short8*)&Ob[row][g + j * 8];
  }
}

// ---------------------------------------------------------------------------
extern "C" void kernel_launch(void* const* d_in, const int* in_sizes, int n_in,
                              void* d_out, int out_size, void* d_ws, size_t ws_size,
                              hipStream_t stream) {
  const float* x       = (const float*)d_in[0];   // [2,2048,2048]
  const float* w_qkv   = (const float*)d_in[1];   // [2048,3072]
  const float* w_dense = (const float*)d_in[2];   // [2048,2048]
  float* out = (float*)d_out;                     // [2,2048,2048] fp32

  char* ws = (char*)d_ws;
  const size_t MB = 1024 * 1024;
  unsigned short* xb    = (unsigned short*)(ws);            // 16 MB (aliased as attn later)
  unsigned short* wqkvT = (unsigned short*)(ws + 16 * MB);  // 12 MB
  unsigned short* wdT   = (unsigned short*)(ws + 28 * MB);  //  8 MB
  unsigned short* Qb    = (unsigned short*)(ws + 36 * MB);  // 16 MB
  unsigned short* Kb    = (unsigned short*)(ws + 52 * MB);  //  4 MB
  unsigned short* VTb   = (unsigned short*)(ws + 56 * MB);  //  4 MB
  float*          rtab  = (float*)(ws + 60 * MB);           //  1 MB  (total 61 MB)
  unsigned short* attn  = xb;   // x no longer needed after qkv GEMM

  const float qscale = 0.08838834764831845f * 1.4426950408889634f; // 1/sqrt(128)*log2e

  rope_table<<<(SEQ * 64) / 256, 256, 0, stream>>>(rtab);
  cvt_f32_bf16<<<(MROWS * EMB) / (256 * 4), 256, 0, stream>>>(x, xb, MROWS * EMB);
  transpose_cvt_dual<<<dim3(NQKV / 32, EMB / 32, 2), 256, 0, stream>>>(
      w_qkv, wqkvT, w_dense, wdT);

  // QKV GEMM with fused table-RoPE in the Q/K epilogue (BN=128, 768 blocks, 3/CU)
  gemm_bt<0><<<dim3(NQKV / 128, MROWS / BM), 256, 0, stream>>>(
      xb, wqkvT, MROWS, NQKV, EMB, nullptr, Qb, Kb, VTb, rtab, qscale);

  attn_kernel<<<dim3(16, NH, NBATCH), 256, 0, stream>>>(Qb, Kb, VTb, attn);

  // dense GEMM (BN=64, 1024 blocks, 4/CU)
  gemm_bt<1><<<dim3(EMB / 64, MROWS / BM), 256, 0, stream>>>(
      attn, wdT, MROWS, EMB, NH * HD, out, nullptr, nullptr, nullptr, nullptr, 0.0f);
}